// Round 13
// baseline (57.318 us; speedup 1.0000x reference)
//
#include <hip/hip_runtime.h>
#include <math.h>

#define J   29
#define CH  3
#define JC  87            // J*CH
#define E0  56
#define B   256
#define T   1024
#define FRAMES (B*T)      // 262144
#define FPC 64            // frames per chunk (= lanes)
#define CPB 4             // chunks per block
#define NBLK (FRAMES/(FPC*CPB)) // 1024
#define CHUNK_F4 1392     // float4s per chunk (5568 floats = 22272 B)
#define BPB (T/(FPC*CPB)) // 4 partials per batch
#define SLOTS 4           // padded nnz per row (overflow beyond)
#define PROWS 32          // padded row count (rows 29..31 = zeros)
#define MAXOV 96          // overflow capacity
#define WAVES 8
#define RPW 4             // rows per wave
#define PFN 3             // float4 prefetch per thread (512*3 >= 1392)

// ---- prep: M = D^-1/2(A+I)D^-1/2, padded-4 slots + row-tagged overflow ----
// pr.x = col*12 (byte offset in PACKED [64][87] layout); ov pr.x = row<<16|col*12
__global__ void prep_kernel(const int* __restrict__ ei,
                            int2* __restrict__ pairs,    // [PROWS*SLOTS]
                            int*  __restrict__ ov_rp,    // [33]
                            int2* __restrict__ ov_pairs) // [MAXOV]
{
    __shared__ float M[J * J];
    __shared__ float dinv[J];
    __shared__ int   cnt_ov[J];
    int tid = threadIdx.x;

    for (int i = tid; i < J * J; i += 64) M[i] = 0.f;
    if (tid < J) {
        int d = 1;
        for (int e = 0; e < E0; ++e) d += (ei[E0 + e] == tid) ? 1 : 0;
        dinv[tid] = rsqrtf((float)d);
    }
    __syncthreads();

    if (tid < J) {
        for (int e = 0; e < E0; ++e) {
            if (ei[E0 + e] == tid) {
                int s = ei[e];
                M[tid * J + s] += dinv[s] * dinv[tid];
            }
        }
        M[tid * J + tid] += dinv[tid] * dinv[tid];
        int c = 0;
        for (int i = 0; i < J; ++i) c += (M[tid * J + i] != 0.f) ? 1 : 0;
        cnt_ov[tid] = (c > SLOTS) ? (c - SLOTS) : 0;
    }
    __syncthreads();

    if (tid == 0) {
        int a = 0;
        for (int j = 0; j < J; ++j) { ov_rp[j] = a; a += cnt_ov[j]; }
        for (int j = J; j <= 32; ++j) ov_rp[j] = a;   // rows 29..31 empty
    }
    __syncthreads();

    if (tid < PROWS) {
        int2 zero; zero.x = 0; zero.y = 0;
        if (tid < J) {
            int s = 0, p = ov_rp[tid];
            for (int i = 0; i < J; ++i) {
                float v = M[tid * J + i];
                if (v != 0.f) {
                    if (s < SLOTS) {
                        int2 pr; pr.x = i * 12; pr.y = __float_as_int(v);
                        pairs[tid * SLOTS + s] = pr;
                    } else {
                        int2 pr; pr.x = (tid << 16) | (i * 12); pr.y = __float_as_int(v);
                        ov_pairs[p++] = pr;
                    }
                    ++s;
                }
            }
            for (; s < SLOTS; ++s) pairs[tid * SLOTS + s] = zero;
        } else {
            for (int s = 0; s < SLOTS; ++s) pairs[tid * SLOTS + s] = zero;
        }
    }
    __syncthreads();
    if (tid == 0) {
        int a = ov_rp[J];
        for (int i = a; i < MAXOV; ++i) { int2 pr; pr.x = 0; pr.y = 0; ov_pairs[i] = pr; }
    }
}

// ---- main: 8 waves/block, reg-staged pipeline, GENEROUS register budget ----
__global__ __launch_bounds__(512, 2)
void gcn_main(const float* __restrict__ x,
              const float* __restrict__ Wp,
              const float* __restrict__ bp,
              const int2* __restrict__ pairs,
              const int*  __restrict__ ov_rp,
              const int2* __restrict__ ov_pairs,
              float* __restrict__ partials) {
    __shared__ float4 xs4[CHUNK_F4];   // 22272 B packed [64 frames][87 floats]
    __shared__ int2   s_ov[MAXOV];

    int tid  = threadIdx.x;
    int lane = tid & 63;
    int wv   = tid >> 6;
    int rowbase = __builtin_amdgcn_readfirstlane(wv * RPW);  // 0,4,...,28

    // wave-uniform tables -> scalar loads (hoisted out of the chunk loop)
    float sW[9], sb[CH];
#pragma unroll
    for (int i = 0; i < 9; ++i) sW[i] = Wp[i];
#pragma unroll
    for (int i = 0; i < CH; ++i) sb[i] = bp[i];
    int ov0 = ov_rp[rowbase], ov1 = ov_rp[rowbase + RPW];
    int2 pr_[RPW][SLOTS];
#pragma unroll
    for (int R = 0; R < RPW; ++R)
#pragma unroll
        for (int sl = 0; sl < SLOTS; ++sl)
            pr_[R][sl] = pairs[(rowbase + R) * SLOTS + sl];
    if (tid < MAXOV) s_ov[tid] = ov_pairs[tid];

    const float4* src4 = (const float4*)x + (size_t)blockIdx.x * (CPB * CHUNK_F4);

    // prologue: prefetch chunk 0 into registers (coalesced; clamped tail
    // duplicates float4 #1391 — benign duplicate write of identical data)
    float4 pf[PFN];
#pragma unroll
    for (int k = 0; k < PFN; ++k) {
        int idx = k * 512 + tid; if (idx > CHUNK_F4 - 1) idx = CHUNK_F4 - 1;
        pf[k] = src4[idx];
    }

    float acc[RPW][CH];
#pragma unroll
    for (int r = 0; r < RPW; ++r)
#pragma unroll
        for (int c = 0; c < CH; ++c) acc[r][c] = 0.f;

#pragma unroll
    for (int c = 0; c < CPB; ++c) {
        __syncthreads();   // xs free (prev chunk consumed); s_ov visible at c=0
#pragma unroll
        for (int k = 0; k < PFN; ++k) {
            int idx = k * 512 + tid; if (idx > CHUNK_F4 - 1) idx = CHUNK_F4 - 1;
            xs4[idx] = pf[k];          // compiler-inserted vmcnt wait on pf
        }
        __syncthreads();   // chunk c visible to all waves

        if (c + 1 < CPB) {
            const float4* s2 = src4 + (c + 1) * CHUNK_F4;
#pragma unroll
            for (int k = 0; k < PFN; ++k) {
                int idx = k * 512 + tid; if (idx > CHUNK_F4 - 1) idx = CHUNK_F4 - 1;
                pf[k] = s2[idx];       // in flight across the compute below
            }
        }

        const char* xf = (const char*)xs4 + lane * 348;

        // phase 1: static 4-slot gather (3 x b32 per slot; 87%32 coprime -> free)
        float y[RPW][CH];
#pragma unroll
        for (int R = 0; R < RPW; ++R) {
            float a0 = 0.f, a1 = 0.f, a2 = 0.f;
#pragma unroll
            for (int sl = 0; sl < SLOTS; ++sl) {
                int2 pr = pr_[R][sl];
                float v = __int_as_float(pr.y);
                const float* q = (const float*)(xf + pr.x);
                a0 += v * q[0];
                a1 += v * q[1];
                a2 += v * q[2];
            }
            y[R][0] = a0; y[R][1] = a1; y[R][2] = a2;
        }
        // phase 2: overflow (runtime-outer, static-inner — proven shape)
        for (int e = ov0; e < ov1; ++e) {
            int2 pr = s_ov[e];
            int row = pr.x >> 16;
            int off = pr.x & 0xFFFF;
            float v = __int_as_float(pr.y);
            const float* q = (const float*)(xf + off);
            float d0 = v * q[0], d1 = v * q[1], d2 = v * q[2];
#pragma unroll
            for (int R = 0; R < RPW; ++R)
                if (row == rowbase + R) { y[R][0] += d0; y[R][1] += d1; y[R][2] += d2; }
        }
        // phase 3: W, bias, ReLU, accumulate
#pragma unroll
        for (int R = 0; R < RPW; ++R)
#pragma unroll
            for (int ch = 0; ch < CH; ++ch) {
                float t = y[R][0] * sW[0 * CH + ch]
                        + y[R][1] * sW[1 * CH + ch]
                        + y[R][2] * sW[2 * CH + ch]
                        + sb[ch];
                acc[R][ch] += fmaxf(t, 0.f);
            }
    }

    // ---- epilogue: transposed LDS write + 87-thread column reduce ----------
    __syncthreads();   // all gather reads done; xs reusable
    float* red = (float*)xs4;     // [64][87]
#pragma unroll
    for (int R = 0; R < RPW; ++R) {
        int j = rowbase + R;
        if (j < J) {
#pragma unroll
            for (int ch = 0; ch < CH; ++ch)
                red[lane * JC + j * CH + ch] = acc[R][ch];
        }
    }
    __syncthreads();
    if (tid < JC) {
        float a = 0.f;
#pragma unroll
        for (int L = 0; L < FPC; ++L) a += red[L * JC + tid];
        partials[(size_t)blockIdx.x * JC + tid] = a;
    }
}

// ---- finalize: mean over frames + fc + sigmoid ------------------------------
__global__ void finalize_kernel(const float* __restrict__ partials,
                                const float* __restrict__ fcW,
                                const float* __restrict__ fcb,
                                float* __restrict__ out) {
    __shared__ float h[JC];
    int b = blockIdx.x, tid = threadIdx.x;
    if (tid < JC) {
        float a = 0.f;
#pragma unroll
        for (int p = 0; p < BPB; ++p)
            a += partials[(size_t)(b * BPB + p) * JC + tid];
        a *= (1.0f / (float)T);
        h[tid] = a;
        out[(size_t)b * JC + tid] = a;
    }
    __syncthreads();
    if (tid < 2) {
        float a = fcb[tid];
        for (int r = 0; r < JC; ++r) a += h[r] * fcW[r * 2 + tid];
        out[(size_t)B * JC + b * 2 + tid] = 1.0f / (1.0f + expf(-a));
    }
}

extern "C" void kernel_launch(void* const* d_in, const int* in_sizes, int n_in,
                              void* d_out, int out_size, void* d_ws, size_t ws_size,
                              hipStream_t stream) {
    const float* x   = (const float*)d_in[0];
    const int*   ei  = (const int*)d_in[1];
    const float* W   = (const float*)d_in[4];
    const float* bb  = (const float*)d_in[5];
    const float* fcW = (const float*)d_in[6];
    const float* fcb = (const float*)d_in[7];

    char* ws = (char*)d_ws;
    int2* pairs    = (int2*)ws;                       // 128 * 8B
    int2* ov_pairs = pairs + PROWS * SLOTS;           // 96 * 8B
    int*  ov_rp    = (int*)(ov_pairs + MAXOV);        // 33 * 4B
    float* partials = (float*)(ws + 4096);            // 1024*87 floats

    prep_kernel<<<1, 64, 0, stream>>>(ei, pairs, ov_rp, ov_pairs);
    gcn_main<<<NBLK, WAVES * 64, 0, stream>>>(x, W, bb, pairs, ov_rp, ov_pairs, partials);
    finalize_kernel<<<B, 128, 0, stream>>>(partials, fcW, fcb, (float*)d_out);
}

// Round 14
// 40.631 us; speedup vs baseline: 1.4107x; 1.4107x over previous
//
#include <hip/hip_runtime.h>
#include <math.h>

#define J   29
#define CH  3
#define JC  87            // J*CH
#define E0  56
#define B   256
#define T   1024
#define FRAMES (B*T)      // 262144
#define FPC 64            // frames per chunk (= lanes)
#define CPB 4             // chunks per block
#define NBLK (FRAMES/(FPC*CPB)) // 1024
#define CHUNK_F4 1392     // float4s per chunk (5568 floats = 22272 B)
#define BPB (T/(FPC*CPB)) // 4 partials per batch
#define SLOTS 4           // padded nnz per row (overflow beyond)
#define PROWS 32          // padded row count (rows 29..31 = zeros)
#define MAXOV 96          // overflow capacity
#define WAVES 8
#define RPW 4             // rows per wave

// ---- prep: M = D^-1/2(A+I)D^-1/2, padded-4 slots + row-tagged overflow ----
// pr.x = col*12 (byte offset in PACKED [64][87] layout); ov pr.x = row<<16|col*12
__global__ void prep_kernel(const int* __restrict__ ei,
                            int2* __restrict__ pairs,    // [PROWS*SLOTS]
                            int*  __restrict__ ov_rp,    // [33]
                            int2* __restrict__ ov_pairs) // [MAXOV]
{
    __shared__ float M[J * J];
    __shared__ float dinv[J];
    __shared__ int   cnt_ov[J];
    int tid = threadIdx.x;

    for (int i = tid; i < J * J; i += 64) M[i] = 0.f;
    if (tid < J) {
        int d = 1;
        for (int e = 0; e < E0; ++e) d += (ei[E0 + e] == tid) ? 1 : 0;
        dinv[tid] = rsqrtf((float)d);
    }
    __syncthreads();

    if (tid < J) {
        for (int e = 0; e < E0; ++e) {
            if (ei[E0 + e] == tid) {
                int s = ei[e];
                M[tid * J + s] += dinv[s] * dinv[tid];
            }
        }
        M[tid * J + tid] += dinv[tid] * dinv[tid];
        int c = 0;
        for (int i = 0; i < J; ++i) c += (M[tid * J + i] != 0.f) ? 1 : 0;
        cnt_ov[tid] = (c > SLOTS) ? (c - SLOTS) : 0;
    }
    __syncthreads();

    if (tid == 0) {
        int a = 0;
        for (int j = 0; j < J; ++j) { ov_rp[j] = a; a += cnt_ov[j]; }
        for (int j = J; j <= 32; ++j) ov_rp[j] = a;   // rows 29..31 empty
    }
    __syncthreads();

    if (tid < PROWS) {
        int2 zero; zero.x = 0; zero.y = 0;
        if (tid < J) {
            int s = 0, p = ov_rp[tid];
            for (int i = 0; i < J; ++i) {
                float v = M[tid * J + i];
                if (v != 0.f) {
                    if (s < SLOTS) {
                        int2 pr; pr.x = i * 12; pr.y = __float_as_int(v);
                        pairs[tid * SLOTS + s] = pr;
                    } else {
                        int2 pr; pr.x = (tid << 16) | (i * 12); pr.y = __float_as_int(v);
                        ov_pairs[p++] = pr;
                    }
                    ++s;
                }
            }
            for (; s < SLOTS; ++s) pairs[tid * SLOTS + s] = zero;
        } else {
            for (int s = 0; s < SLOTS; ++s) pairs[tid * SLOTS + s] = zero;
        }
    }
    __syncthreads();
    if (tid == 0) {
        int a = ov_rp[J];
        for (int i = a; i < MAXOV; ++i) { int2 pr; pr.x = 0; pr.y = 0; ov_pairs[i] = pr; }
    }
}

// ---- main: 8 waves/block, reg-staged pipeline, NAMED prefetch registers ----
__global__ __launch_bounds__(512, 2)
void gcn_main(const float* __restrict__ x,
              const float* __restrict__ Wp,
              const float* __restrict__ bp,
              const int2* __restrict__ pairs,
              const int*  __restrict__ ov_rp,
              const int2* __restrict__ ov_pairs,
              float* __restrict__ partials) {
    __shared__ float4 xs4[CHUNK_F4];   // 22272 B packed [64 frames][87 floats]
    __shared__ int2   s_ov[MAXOV];

    int tid  = threadIdx.x;
    int lane = tid & 63;
    int wv   = tid >> 6;
    int rowbase = __builtin_amdgcn_readfirstlane(wv * RPW);  // 0,4,...,28

    // wave-uniform tables -> scalar loads (loop-invariant, compiler hoists)
    float sW[9], sb[CH];
#pragma unroll
    for (int i = 0; i < 9; ++i) sW[i] = Wp[i];
#pragma unroll
    for (int i = 0; i < CH; ++i) sb[i] = bp[i];
    int ov0 = ov_rp[rowbase], ov1 = ov_rp[rowbase + RPW];
    if (tid < MAXOV) s_ov[tid] = ov_pairs[tid];

    const float4* src4 = (const float4*)x + (size_t)blockIdx.x * (CPB * CHUNK_F4);

    // clamped third index (tid and 512+tid are always < 1392)
    int i2 = 1024 + tid; if (i2 > CHUNK_F4 - 1) i2 = CHUNK_F4 - 1;

    // prologue: prefetch chunk 0 into NAMED registers (no array -> no scratch)
    float4 pf0 = src4[tid];
    float4 pf1 = src4[512 + tid];
    float4 pf2 = src4[i2];          // tail dupes float4 #1391 — benign

    float acc[RPW][CH];
#pragma unroll
    for (int r = 0; r < RPW; ++r)
#pragma unroll
        for (int c = 0; c < CH; ++c) acc[r][c] = 0.f;

#pragma unroll
    for (int c = 0; c < CPB; ++c) {
        __syncthreads();   // xs free (prev chunk consumed); s_ov visible at c=0
        xs4[tid]       = pf0;       // compiler-inserted vmcnt waits
        xs4[512 + tid] = pf1;
        xs4[i2]        = pf2;       // clamped lanes rewrite same value — benign
        __syncthreads();   // chunk c visible to all waves

        if (c + 1 < CPB) {
            const float4* s2 = src4 + (c + 1) * CHUNK_F4;
            pf0 = s2[tid];          // in flight across the compute below
            pf1 = s2[512 + tid];
            pf2 = s2[i2];
        }

        const char* xf = (const char*)xs4 + lane * 348;

        // phase 1: static 4-slot gather; pair table read via uniform s_loads
        float y[RPW][CH];
#pragma unroll
        for (int R = 0; R < RPW; ++R) {
            float a0 = 0.f, a1 = 0.f, a2 = 0.f;
#pragma unroll
            for (int sl = 0; sl < SLOTS; ++sl) {
                int2 pr = pairs[(rowbase + R) * SLOTS + sl];  // uniform -> SGPR
                float v = __int_as_float(pr.y);
                const float* q = (const float*)(xf + pr.x);
                a0 += v * q[0];
                a1 += v * q[1];
                a2 += v * q[2];
            }
            y[R][0] = a0; y[R][1] = a1; y[R][2] = a2;
        }
        // phase 2: overflow (runtime-outer, static-inner — proven shape)
        for (int e = ov0; e < ov1; ++e) {
            int2 pr = s_ov[e];
            int row = pr.x >> 16;
            int off = pr.x & 0xFFFF;
            float v = __int_as_float(pr.y);
            const float* q = (const float*)(xf + off);
            float d0 = v * q[0], d1 = v * q[1], d2 = v * q[2];
#pragma unroll
            for (int R = 0; R < RPW; ++R)
                if (row == rowbase + R) { y[R][0] += d0; y[R][1] += d1; y[R][2] += d2; }
        }
        // phase 3: W, bias, ReLU, accumulate
#pragma unroll
        for (int R = 0; R < RPW; ++R)
#pragma unroll
            for (int ch = 0; ch < CH; ++ch) {
                float t = y[R][0] * sW[0 * CH + ch]
                        + y[R][1] * sW[1 * CH + ch]
                        + y[R][2] * sW[2 * CH + ch]
                        + sb[ch];
                acc[R][ch] += fmaxf(t, 0.f);
            }
    }

    // ---- epilogue: transposed LDS write + 87-thread column reduce ----------
    __syncthreads();   // all gather reads done; xs reusable
    float* red = (float*)xs4;     // [64][87]
#pragma unroll
    for (int R = 0; R < RPW; ++R) {
        int j = rowbase + R;
        if (j < J) {
#pragma unroll
            for (int ch = 0; ch < CH; ++ch)
                red[lane * JC + j * CH + ch] = acc[R][ch];
        }
    }
    __syncthreads();
    if (tid < JC) {
        float a = 0.f;
#pragma unroll
        for (int L = 0; L < FPC; ++L) a += red[L * JC + tid];
        partials[(size_t)blockIdx.x * JC + tid] = a;
    }
}

// ---- finalize: mean over frames + fc + sigmoid ------------------------------
__global__ void finalize_kernel(const float* __restrict__ partials,
                                const float* __restrict__ fcW,
                                const float* __restrict__ fcb,
                                float* __restrict__ out) {
    __shared__ float h[JC];
    int b = blockIdx.x, tid = threadIdx.x;
    if (tid < JC) {
        float a = 0.f;
#pragma unroll
        for (int p = 0; p < BPB; ++p)
            a += partials[(size_t)(b * BPB + p) * JC + tid];
        a *= (1.0f / (float)T);
        h[tid] = a;
        out[(size_t)b * JC + tid] = a;
    }
    __syncthreads();
    if (tid < 2) {
        float a = fcb[tid];
        for (int r = 0; r < JC; ++r) a += h[r] * fcW[r * 2 + tid];
        out[(size_t)B * JC + b * 2 + tid] = 1.0f / (1.0f + expf(-a));
    }
}

extern "C" void kernel_launch(void* const* d_in, const int* in_sizes, int n_in,
                              void* d_out, int out_size, void* d_ws, size_t ws_size,
                              hipStream_t stream) {
    const float* x   = (const float*)d_in[0];
    const int*   ei  = (const int*)d_in[1];
    const float* W   = (const float*)d_in[4];
    const float* bb  = (const float*)d_in[5];
    const float* fcW = (const float*)d_in[6];
    const float* fcb = (const float*)d_in[7];

    char* ws = (char*)d_ws;
    int2* pairs    = (int2*)ws;                       // 128 * 8B
    int2* ov_pairs = pairs + PROWS * SLOTS;           // 96 * 8B
    int*  ov_rp    = (int*)(ov_pairs + MAXOV);        // 33 * 4B
    float* partials = (float*)(ws + 4096);            // 1024*87 floats

    prep_kernel<<<1, 64, 0, stream>>>(ei, pairs, ov_rp, ov_pairs);
    gcn_main<<<NBLK, WAVES * 64, 0, stream>>>(x, W, bb, pairs, ov_rp, ov_pairs, partials);
    finalize_kernel<<<B, 128, 0, stream>>>(partials, fcW, fcb, (float*)d_out);
}